// Round 1
// baseline (116.374 us; speedup 1.0000x reference)
//
#include <hip/hip_runtime.h>
#include <hip/hip_fp16.h>
#include <cfloat>
#include <cmath>

#define N_NODES 20000
#define MAXD 32
#define F 128

// stage-2 MFMA tiling
#define MTILE 64
#define NBLK ((N_NODES + MTILE - 1) / MTILE)  // 313 blocks
#define MPAD (NBLK * MTILE)                   // 20032 rows in workspace
#define WT_PITCH 136                          // 272B pitch: spreads b128 lane windows across banks

typedef _Float16 half8 __attribute__((ext_vector_type(8)));
typedef float f32x4 __attribute__((ext_vector_type(4)));

// ---------------- stage 1: trimmed-mean aggregation (R11 core, split-store epilogue) ----
// CRITICAL invariants (measured):
//  * node index must be blockIdx-derived (scalar) — threadIdx-derived i =>
//    ~10x VALU blowup (R6: 415us).
//  * private arrays must be pow2-sized with static indices — non-pow2 triggers
//    promote-to-LDS + scratch spill (R8: LDS_Block=10240, 140us).
//  * 1 node / 128-thread block. Exact-n templates (R11): compile-time b,
//    direct-register rank extraction, pad-pruned sort network -> 57 -> ~38us.
//  * Near the random-gather memory floor (~169 MB scattered 512B segments
//    at ~4.4 TB/s effective L2/L3).
//  * NEW: epilogue stores accum as fp16 hi/lo split (2x2B, same total bytes as
//    one f32) so stage 2 can run on the f16 MFMA pipe. a = hi + lo captures
//    ~22 mantissa bits; split error ~2^-22 rel, far below tolerance.

template <int SZ, int NV>
__device__ __forceinline__ void oe_sort_n(float (&a)[SZ]) {
#pragma unroll
  for (int p = 1; p < SZ; p <<= 1) {
#pragma unroll
    for (int q = p; q >= 1; q >>= 1) {
#pragma unroll
      for (int j = q % p; j <= SZ - 1 - q; j += 2 * q) {
#pragma unroll
        for (int i = 0; i < q; ++i) {
          int x = i + j, y = i + j + q;
          if (y < NV && (x / (2 * p)) == (y / (2 * p))) {  // y<NV ⊆ y<SZ
            float mn = fminf(a[x], a[y]);
            float mx = fmaxf(a[x], a[y]);
            a[x] = mn;
            a[y] = mx;
          }
        }
      }
    }
  }
}

// b = max(min(n/2 - (1-n%2), (int)floor_f32(n*0.45f)), 1) — f32 mult matches
// jnp exactly (e.g. n=20: 20*0.449999988f = 8.9999998 -> 8, not 9).
template <int N>
struct TrimB {
  static constexpr int b_raw = N / 2 - (1 - (N & 1));
  static constexpr int b_cap = (int)((float)N * 0.45f);  // trunc == floor (pos)
  static constexpr int b_min = b_raw < b_cap ? b_raw : b_cap;
  static constexpr int value = b_min > 1 ? b_min : 1;
};

// Exact trimmed sum, exact-n specialization. Stable-rank semantics match
// jnp.argsort (ties by slot). Fast path: no equal-key run straddles either
// trim boundary -> pure value test. Slow path (rare): exact stable-rank scan.
template <int SZ, int N>
__device__ __forceinline__ float trimmed_sum_n(const float* __restrict__ h,
                                               const float* __restrict__ norm,
                                               const int* __restrict__ nbr_row,
                                               int f) {
  constexpr int B = TrimB<N>::value;
  constexpr int NB = N - B;

  float ko[SZ];
  float nrm[SZ];  // block-uniform -> SGPRs
  float k[SZ];
#pragma unroll
  for (int d = 0; d < N; ++d) {
    int src = nbr_row[d];       // scalar load
    nrm[d] = norm[src];         // scalar load
    ko[d] = h[src * F + f];     // vector load, coalesced 256B/wave
    k[d] = ko[d];
  }
#pragma unroll
  for (int d = N; d < SZ; ++d) k[d] = FLT_MAX;  // pads sort past all valid keys

  oe_sort_n<SZ, N>(k);

  const float lo  = k[B];       // compile-time positions -> direct reg reads
  const float hi  = k[NB - 1];
  const float lom = k[B - 1];
  const float him = k[NB];

  float sum = 0.f;
  if ((lom < lo) & (hi < him)) {
#pragma unroll
    for (int d = 0; d < N; ++d) {
      bool keep = (ko[d] >= lo) & (ko[d] <= hi);
      sum = fmaf(keep ? ko[d] : 0.f, nrm[d], sum);
    }
  } else {
    int c_lt_lo = 0, c_lt_hi = 0;
#pragma unroll
    for (int d = 0; d < N; ++d) {
      c_lt_lo += (ko[d] < lo) ? 1 : 0;
      c_lt_hi += (ko[d] < hi) ? 1 : 0;
    }
    int run_lo = 0, run_hi = 0;
#pragma unroll
    for (int d = 0; d < N; ++d) {
      const float kd = ko[d];
      const float m = kd * nrm[d];
      const bool eql = (kd == lo);
      const bool eqh = (kd == hi);
      const bool lh = (lo < hi);
      const bool btw = (kd > lo) & (kd < hi);
      const int r_lo = c_lt_lo + run_lo;  // stable rank if kd==lo
      const int r_hi = c_lt_hi + run_hi;  // stable rank if kd==hi
      const bool inc = btw
                     | (eql & (r_lo >= B) & (lh | (r_lo < NB)))
                     | (lh & eqh & (r_hi < NB));
      sum += inc ? m : 0.f;
      run_lo += eql ? 1 : 0;
      run_hi += eqh ? 1 : 0;
    }
  }
  return sum;
}

__device__ __forceinline__ void store_split(_Float16* __restrict__ Ah,
                                            _Float16* __restrict__ Al,
                                            int idx, float v) {
  _Float16 hi = (_Float16)v;           // rne f32->f16
  Ah[idx] = hi;
  Al[idx] = (_Float16)(v - (float)hi); // residual, exact subtraction
}

__global__ __launch_bounds__(128) void gcn_stage1(const float* __restrict__ h,
                                                  const float* __restrict__ norm,
                                                  const int* __restrict__ nbr,
                                                  const int* __restrict__ deg,
                                                  _Float16* __restrict__ Ah,
                                                  _Float16* __restrict__ Al) {
  const int i = blockIdx.x;       // MUST stay blockIdx-derived (scalar)
  const int f = threadIdx.x;
  const int n = deg[i];           // scalar
  const float ni = norm[i];
  const float hif = h[i * F + f];
  const int idx = i * F + f;

  if (n <= 3) {  // N_NEIGH_THRESHOLD branch
    store_split(Ah, Al, idx, (float)n * hif * ni * ni);
    return;
  }

  const int* nbr_row = nbr + i * MAXD;
  float ts;
  int b;
  switch (n) {  // scalar switch; each case fully compile-time specialized
#define TS_CASE(NN, SS) \
    case NN: ts = trimmed_sum_n<SS, NN>(h, norm, nbr_row, f); b = TrimB<NN>::value; break;
    TS_CASE(4, 4)
    TS_CASE(5, 8) TS_CASE(6, 8) TS_CASE(7, 8) TS_CASE(8, 8)
    TS_CASE(9, 16) TS_CASE(10, 16) TS_CASE(11, 16) TS_CASE(12, 16)
    TS_CASE(13, 16) TS_CASE(14, 16) TS_CASE(15, 16) TS_CASE(16, 16)
    TS_CASE(17, 32) TS_CASE(18, 32) TS_CASE(19, 32) TS_CASE(20, 32)
    TS_CASE(21, 32) TS_CASE(22, 32) TS_CASE(23, 32) TS_CASE(24, 32)
    TS_CASE(25, 32) TS_CASE(26, 32) TS_CASE(27, 32) TS_CASE(28, 32)
    TS_CASE(29, 32) TS_CASE(30, 32) TS_CASE(31, 32)
    default: ts = trimmed_sum_n<32, 32>(h, norm, nbr_row, f); b = TrimB<32>::value; break;
#undef TS_CASE
  }

  store_split(Ah, Al, idx, (ts + hif * ni * (float)(2 * b)) * ni);
}

// ---------------- stage 2: out = relu(accum @ W + bias), fp16x2-split MFMA ----
// Old fp32 SGEMM sat at ~18us = 36 TF = 23% of the 157 TF vector-fp32 peak with
// only 20.5 MB of traffic — neither roofline. CDNA4 has no fp32 MFMA, so run
// a = (a_hi + a_lo), w = (w_hi + w_lo) on the f16 matrix pipe (1955 TF) with
// the 3 dominant products: ah*wh + ah*wl + al*wh (al*wl ~ 2^-24, dropped).
//  * W (64 KB) converted once per block into LDS, TRANSPOSED [n][k] hi/lo,
//    pitch 136 halfs (272 B) so the wave's b128 windows land on all 8 aligned
//    4-bank windows (~2-way, free per m136).
//  * A fragments load straight from global (L2/L3-resident, written pre-split
//    by stage 1): lane l reads rows (l&15), 8 contiguous k at (l>>4)*8 —
//    the verified gfx950 16x16x32 operand mapping. No A staging, no K barriers.
//  * 313 blocks x 64 rows; per wave (32 cols): 4 rf x 2 cf x 4 kc x 3 = 96 MFMA.
//  * Rows 20000..20031 are workspace poison: they only contaminate D-rows
//    20000+ (MFMA row = A row) and stores are guarded by row < N_NODES.
__global__ __launch_bounds__(256) void gcn_gemm_mfma(
    const _Float16* __restrict__ Ah, const _Float16* __restrict__ Al,
    const float* __restrict__ W, const float* __restrict__ bias,
    float* __restrict__ out) {
  __shared__ _Float16 Wt[2][F][WT_PITCH];  // [hi/lo][n][k], 69.6 KB
  const int t = threadIdx.x;

  // convert + transpose W: 16384 elems, 64/thread, global reads coalesced.
#pragma unroll 4
  for (int i = 0; i < 64; ++i) {
    int idx = i * 256 + t;
    int k = idx >> 7, n = idx & 127;
    float w = W[idx];
    _Float16 hi = (_Float16)w;
    Wt[0][n][k] = hi;
    Wt[1][n][k] = (_Float16)(w - (float)hi);
  }
  __syncthreads();

  const int lane = t & 63;
  const int wv = t >> 6;        // wave id -> cols [wv*32, wv*32+32)
  const int l16 = lane & 15;
  const int kg = lane >> 4;     // k-group 0..3 (8 k each)
  const int row0 = blockIdx.x * MTILE;
  const int colb = wv * 32;

  f32x4 acc[4][2];
#pragma unroll
  for (int rf = 0; rf < 4; ++rf)
#pragma unroll
    for (int cf = 0; cf < 2; ++cf) acc[rf][cf] = (f32x4){0.f, 0.f, 0.f, 0.f};

#pragma unroll
  for (int kc = 0; kc < F; kc += 32) {
    half8 ah[4], al[4], bh[2], bl[2];
#pragma unroll
    for (int rf = 0; rf < 4; ++rf) {
      const int row = row0 + rf * 16 + l16;
      const size_t off = (size_t)row * F + kc + kg * 8;  // 16B-aligned
      ah[rf] = *(const half8*)(Ah + off);
      al[rf] = *(const half8*)(Al + off);
    }
#pragma unroll
    for (int cf = 0; cf < 2; ++cf) {
      const int n = colb + cf * 16 + l16;
      bh[cf] = *(const half8*)(&Wt[0][n][kc + kg * 8]);  // ds_read_b128
      bl[cf] = *(const half8*)(&Wt[1][n][kc + kg * 8]);
    }
#pragma unroll
    for (int rf = 0; rf < 4; ++rf)
#pragma unroll
      for (int cf = 0; cf < 2; ++cf) {
        acc[rf][cf] = __builtin_amdgcn_mfma_f32_16x16x32_f16(ah[rf], bh[cf], acc[rf][cf], 0, 0, 0);
        acc[rf][cf] = __builtin_amdgcn_mfma_f32_16x16x32_f16(ah[rf], bl[cf], acc[rf][cf], 0, 0, 0);
        acc[rf][cf] = __builtin_amdgcn_mfma_f32_16x16x32_f16(al[rf], bh[cf], acc[rf][cf], 0, 0, 0);
      }
  }

  // epilogue: bias + relu. D mapping: col = lane&15 (+cf*16+colb),
  // row = rf*16 + (lane>>4)*4 + r  (verified C/D layout, m89).
#pragma unroll
  for (int cf = 0; cf < 2; ++cf) {
    const int col = colb + cf * 16 + l16;
    const float bv = bias[col];
#pragma unroll
    for (int rf = 0; rf < 4; ++rf) {
#pragma unroll
      for (int r = 0; r < 4; ++r) {
        const int row = row0 + rf * 16 + kg * 4 + r;
        if (row < N_NODES) {
          out[(size_t)row * F + col] = fmaxf(acc[rf][cf][r] + bv, 0.f);
        }
      }
    }
  }
}

extern "C" void kernel_launch(void* const* d_in, const int* in_sizes, int n_in,
                              void* d_out, int out_size, void* d_ws, size_t ws_size,
                              hipStream_t stream) {
  const float* h = (const float*)d_in[0];
  const float* norm = (const float*)d_in[1];
  const float* weight = (const float*)d_in[2];
  const float* bias = (const float*)d_in[3];
  const int* nbr = (const int*)d_in[4];
  const int* deg = (const int*)d_in[5];
  float* out = (float*)d_out;

  _Float16* Ah = (_Float16*)d_ws;                  // MPAD*F halfs = 5.13 MB
  _Float16* Al = Ah + (size_t)MPAD * F;            // another 5.13 MB

  gcn_stage1<<<N_NODES, 128, 0, stream>>>(h, norm, nbr, deg, Ah, Al);
  gcn_gemm_mfma<<<NBLK, 256, 0, stream>>>(Ah, Al, weight, bias, out);
}

// Round 2
// 112.350 us; speedup vs baseline: 1.0358x; 1.0358x over previous
//
#include <hip/hip_runtime.h>
#include <hip/hip_fp16.h>
#include <cfloat>
#include <cmath>

#define N_NODES 20000
#define MAXD 32
#define F 128

// stage-2 MFMA tiling: 20000 = 625 * 32 exactly -> no remainder, no guards
#define MTILE 32
#define NBLK (N_NODES / MTILE)  // 625 blocks

typedef _Float16 half8 __attribute__((ext_vector_type(8)));
typedef float f32x4 __attribute__((ext_vector_type(4)));
typedef unsigned int u32x4 __attribute__((ext_vector_type(4)));
typedef unsigned short us8v __attribute__((ext_vector_type(8)));

// ---------------- stage 1: trimmed-mean aggregation (R11 core) ---------------
// CRITICAL invariants (measured):
//  * node index must be blockIdx-derived (scalar) — threadIdx-derived i =>
//    ~10x VALU blowup (R6: 415us).
//  * private arrays must be pow2-sized with static indices — non-pow2 triggers
//    promote-to-LDS + scratch spill (R8: LDS_Block=10240, 140us).
//  * 1 node / 128-thread block. Exact-n templates (R11): compile-time b,
//    direct-register rank extraction, pad-pruned sort network -> ~38us.
//  * Near the random-gather memory floor (~169 MB scattered 512B segments
//    at ~4.4 TB/s effective L2/L3).
//  * Store path: ONE packed u32 per lane (fp16 hi | lo<<16) — identical
//    coalescing to the f32 baseline. (R1 regression suspect: two 2B stores
//    to two buffers = half-rate write transactions.)
//  * Blocks 0..15 additionally pre-split/transpose W (64KB) into workspace so
//    stage 2 needs no LDS prologue. 8 elems/thread — negligible.

template <int SZ, int NV>
__device__ __forceinline__ void oe_sort_n(float (&a)[SZ]) {
#pragma unroll
  for (int p = 1; p < SZ; p <<= 1) {
#pragma unroll
    for (int q = p; q >= 1; q >>= 1) {
#pragma unroll
      for (int j = q % p; j <= SZ - 1 - q; j += 2 * q) {
#pragma unroll
        for (int i = 0; i < q; ++i) {
          int x = i + j, y = i + j + q;
          if (y < NV && (x / (2 * p)) == (y / (2 * p))) {  // y<NV ⊆ y<SZ
            float mn = fminf(a[x], a[y]);
            float mx = fmaxf(a[x], a[y]);
            a[x] = mn;
            a[y] = mx;
          }
        }
      }
    }
  }
}

// b = max(min(n/2 - (1-n%2), (int)floor_f32(n*0.45f)), 1) — f32 mult matches
// jnp exactly (e.g. n=20: 20*0.449999988f = 8.9999998 -> 8, not 9).
template <int N>
struct TrimB {
  static constexpr int b_raw = N / 2 - (1 - (N & 1));
  static constexpr int b_cap = (int)((float)N * 0.45f);  // trunc == floor (pos)
  static constexpr int b_min = b_raw < b_cap ? b_raw : b_cap;
  static constexpr int value = b_min > 1 ? b_min : 1;
};

// Exact trimmed sum, exact-n specialization. Stable-rank semantics match
// jnp.argsort (ties by slot). Fast path: no equal-key run straddles either
// trim boundary -> pure value test. Slow path (rare): exact stable-rank scan.
template <int SZ, int N>
__device__ __forceinline__ float trimmed_sum_n(const float* __restrict__ h,
                                               const float* __restrict__ norm,
                                               const int* __restrict__ nbr_row,
                                               int f) {
  constexpr int B = TrimB<N>::value;
  constexpr int NB = N - B;

  float ko[SZ];
  float nrm[SZ];  // block-uniform -> SGPRs
  float k[SZ];
#pragma unroll
  for (int d = 0; d < N; ++d) {
    int src = nbr_row[d];       // scalar load
    nrm[d] = norm[src];         // scalar load
    ko[d] = h[src * F + f];     // vector load, coalesced 256B/wave
    k[d] = ko[d];
  }
#pragma unroll
  for (int d = N; d < SZ; ++d) k[d] = FLT_MAX;  // pads sort past all valid keys

  oe_sort_n<SZ, N>(k);

  const float lo  = k[B];       // compile-time positions -> direct reg reads
  const float hi  = k[NB - 1];
  const float lom = k[B - 1];
  const float him = k[NB];

  float sum = 0.f;
  if ((lom < lo) & (hi < him)) {
#pragma unroll
    for (int d = 0; d < N; ++d) {
      bool keep = (ko[d] >= lo) & (ko[d] <= hi);
      sum = fmaf(keep ? ko[d] : 0.f, nrm[d], sum);
    }
  } else {
    int c_lt_lo = 0, c_lt_hi = 0;
#pragma unroll
    for (int d = 0; d < N; ++d) {
      c_lt_lo += (ko[d] < lo) ? 1 : 0;
      c_lt_hi += (ko[d] < hi) ? 1 : 0;
    }
    int run_lo = 0, run_hi = 0;
#pragma unroll
    for (int d = 0; d < N; ++d) {
      const float kd = ko[d];
      const float m = kd * nrm[d];
      const bool eql = (kd == lo);
      const bool eqh = (kd == hi);
      const bool lh = (lo < hi);
      const bool btw = (kd > lo) & (kd < hi);
      const int r_lo = c_lt_lo + run_lo;  // stable rank if kd==lo
      const int r_hi = c_lt_hi + run_hi;  // stable rank if kd==hi
      const bool inc = btw
                     | (eql & (r_lo >= B) & (lh | (r_lo < NB)))
                     | (lh & eqh & (r_hi < NB));
      sum += inc ? m : 0.f;
      run_lo += eql ? 1 : 0;
      run_hi += eqh ? 1 : 0;
    }
  }
  return sum;
}

// a = hi + lo captures ~22 mantissa bits; packed into one u32 (hi low16).
__device__ __forceinline__ unsigned int split_pack(float v) {
  _Float16 hi = (_Float16)v;            // rne f32->f16
  _Float16 lo = (_Float16)(v - (float)hi);
  unsigned short hb = __builtin_bit_cast(unsigned short, hi);
  unsigned short lb = __builtin_bit_cast(unsigned short, lo);
  return (unsigned int)hb | ((unsigned int)lb << 16);
}

__global__ __launch_bounds__(128) void gcn_stage1(const float* __restrict__ h,
                                                  const float* __restrict__ norm,
                                                  const int* __restrict__ nbr,
                                                  const int* __restrict__ deg,
                                                  const float* __restrict__ W,
                                                  unsigned int* __restrict__ Ap,
                                                  _Float16* __restrict__ Whl) {
  const int i = blockIdx.x;       // MUST stay blockIdx-derived (scalar)
  const int f = threadIdx.x;

  // blocks 0..15: also pre-split + transpose W into workspace for stage 2.
  // Whl[0][n][k] = hi, Whl[16384 + n*F + k] = lo. 2048 x 2B stores/block.
  if (i < 16) {
    const int e0 = (i * 128 + f) * 8;
#pragma unroll
    for (int j = 0; j < 8; ++j) {
      const int e = e0 + j;
      const int k = e >> 7, n = e & 127;
      const float w = W[e];
      const _Float16 whi = (_Float16)w;
      Whl[n * F + k] = whi;
      Whl[16384 + n * F + k] = (_Float16)(w - (float)whi);
    }
  }

  const int n = deg[i];           // scalar
  const float ni = norm[i];
  const float hif = h[i * F + f];
  const int idx = i * F + f;

  if (n <= 3) {  // N_NEIGH_THRESHOLD branch
    Ap[idx] = split_pack((float)n * hif * ni * ni);
    return;
  }

  const int* nbr_row = nbr + i * MAXD;
  float ts;
  int b;
  switch (n) {  // scalar switch; each case fully compile-time specialized
#define TS_CASE(NN, SS) \
    case NN: ts = trimmed_sum_n<SS, NN>(h, norm, nbr_row, f); b = TrimB<NN>::value; break;
    TS_CASE(4, 4)
    TS_CASE(5, 8) TS_CASE(6, 8) TS_CASE(7, 8) TS_CASE(8, 8)
    TS_CASE(9, 16) TS_CASE(10, 16) TS_CASE(11, 16) TS_CASE(12, 16)
    TS_CASE(13, 16) TS_CASE(14, 16) TS_CASE(15, 16) TS_CASE(16, 16)
    TS_CASE(17, 32) TS_CASE(18, 32) TS_CASE(19, 32) TS_CASE(20, 32)
    TS_CASE(21, 32) TS_CASE(22, 32) TS_CASE(23, 32) TS_CASE(24, 32)
    TS_CASE(25, 32) TS_CASE(26, 32) TS_CASE(27, 32) TS_CASE(28, 32)
    TS_CASE(29, 32) TS_CASE(30, 32) TS_CASE(31, 32)
    default: ts = trimmed_sum_n<32, 32>(h, norm, nbr_row, f); b = TrimB<32>::value; break;
#undef TS_CASE
  }

  Ap[idx] = split_pack((ts + hif * ni * (float)(2 * b)) * ni);
}

// ---------------- stage 2: out = relu(accum @ W + bias), fp16x2-split MFMA ----
// fp32 SGEMM sat at ~18us = 36 TF = 23% of the 157 TF vector-fp32 peak — CDNA4
// has no fp32 MFMA, so run a=(ah+al), w=(wh+wl) on the f16 MFMA pipe with the
// 3 dominant products ah*wh + ah*wl + al*wh (al*wl ~ 2^-22 rel, dropped).
// Validated by R1 refcheck (passed, absmax 0.0078). R2 restructure:
//  * NO LDS, NO barriers, NO per-block W conversion: W pre-split by stage 1
//    into a 64KB global buffer (hot in every XCD L2 after first touch).
//  * A fragments load packed u32 straight from global (L2/L3-resident),
//    deinterleaved with 2 shufflevectors (v_perm_b32, VALU pipe ∥ MFMA pipe).
//    Operand mapping (lane&15 = row/col, lane>>4 = k-group of 8) is the
//    R1-refcheck-verified gfx950 16x16x32 layout.
//  * MTILE=32 -> 625 blocks (exact: 20000=625*32, no guards), ~2.4 blocks/CU
//    for latency hiding (R1 had 1.2 + a serial 64-iter prologue per block).
//  * Per wave (32 cols x 32 rows): 2rf x 2cf x 4kc x 3 = 48 MFMA; pure-MFMA
//    time is ~0.25us total — this kernel is latency/BW, floor ~4-5us
//    (10.2MB A reads + 10.2MB out writes).
__global__ __launch_bounds__(256) void gcn_gemm_mfma(
    const unsigned int* __restrict__ Ap, const _Float16* __restrict__ Whl,
    const float* __restrict__ bias, float* __restrict__ out) {
  const int t = threadIdx.x;
  const int lane = t & 63;
  const int wv = t >> 6;        // wave id -> cols [wv*32, wv*32+32)
  const int l16 = lane & 15;
  const int kg = lane >> 4;     // k-group 0..3 (8 k each)
  const int row0 = blockIdx.x * MTILE;
  const int colb = wv * 32;

  f32x4 acc[2][2];
#pragma unroll
  for (int rf = 0; rf < 2; ++rf)
#pragma unroll
    for (int cf = 0; cf < 2; ++cf) acc[rf][cf] = (f32x4){0.f, 0.f, 0.f, 0.f};

#pragma unroll
  for (int kc = 0; kc < F; kc += 32) {
    half8 ah[2], al[2], bh[2], bl[2];
#pragma unroll
    for (int rf = 0; rf < 2; ++rf) {
      const int row = row0 + rf * 16 + l16;
      const unsigned int* p = Ap + (size_t)row * F + kc + kg * 8;
      u32x4 p0 = *(const u32x4*)p;        // 2x dwordx4, 16B aligned
      u32x4 p1 = *(const u32x4*)(p + 4);
      us8v s0 = __builtin_bit_cast(us8v, p0);  // {h0,l0,h1,l1,...}
      us8v s1 = __builtin_bit_cast(us8v, p1);
      ah[rf] = __builtin_bit_cast(half8,
          (us8v)__builtin_shufflevector(s0, s1, 0, 2, 4, 6, 8, 10, 12, 14));
      al[rf] = __builtin_bit_cast(half8,
          (us8v)__builtin_shufflevector(s0, s1, 1, 3, 5, 7, 9, 11, 13, 15));
    }
#pragma unroll
    for (int cf = 0; cf < 2; ++cf) {
      const int n = colb + cf * 16 + l16;
      bh[cf] = *(const half8*)(Whl + n * F + kc + kg * 8);
      bl[cf] = *(const half8*)(Whl + 16384 + n * F + kc + kg * 8);
    }
#pragma unroll
    for (int rf = 0; rf < 2; ++rf)
#pragma unroll
      for (int cf = 0; cf < 2; ++cf) {
        acc[rf][cf] = __builtin_amdgcn_mfma_f32_16x16x32_f16(ah[rf], bh[cf], acc[rf][cf], 0, 0, 0);
        acc[rf][cf] = __builtin_amdgcn_mfma_f32_16x16x32_f16(ah[rf], bl[cf], acc[rf][cf], 0, 0, 0);
        acc[rf][cf] = __builtin_amdgcn_mfma_f32_16x16x32_f16(al[rf], bh[cf], acc[rf][cf], 0, 0, 0);
      }
  }

  // epilogue: bias + relu. D mapping: col = lane&15 (+cf*16+colb),
  // row = rf*16 + (lane>>4)*4 + r  (verified C/D layout, m89 + R1 refcheck).
#pragma unroll
  for (int cf = 0; cf < 2; ++cf) {
    const int col = colb + cf * 16 + l16;
    const float bv = bias[col];
#pragma unroll
    for (int rf = 0; rf < 2; ++rf) {
#pragma unroll
      for (int r = 0; r < 4; ++r) {
        const int row = row0 + rf * 16 + kg * 4 + r;
        out[(size_t)row * F + col] = fmaxf(acc[rf][cf][r] + bv, 0.f);
      }
    }
  }
}

extern "C" void kernel_launch(void* const* d_in, const int* in_sizes, int n_in,
                              void* d_out, int out_size, void* d_ws, size_t ws_size,
                              hipStream_t stream) {
  const float* h = (const float*)d_in[0];
  const float* norm = (const float*)d_in[1];
  const float* weight = (const float*)d_in[2];
  const float* bias = (const float*)d_in[3];
  const int* nbr = (const int*)d_in[4];
  const int* deg = (const int*)d_in[5];
  float* out = (float*)d_out;

  unsigned int* Ap = (unsigned int*)d_ws;             // 20000*128*4 = 10.24 MB
  _Float16* Whl = (_Float16*)(Ap + (size_t)N_NODES * F);  // 64 KB hi+lo split W

  gcn_stage1<<<N_NODES, 128, 0, stream>>>(h, norm, nbr, deg, weight, Ap, Whl);
  gcn_gemm_mfma<<<NBLK, 256, 0, stream>>>(Ap, Whl, bias, out);
}